// Round 1
// baseline (996.658 us; speedup 1.0000x reference)
//
#include <hip/hip_runtime.h>
#include <math.h>

#define N_NODES 50000
#define N_EDGES 800000
#define EP (N_EDGES + N_NODES) /* 850000 edges incl self-loops */
#define NEG_SLOPE 0.2f

// ---------------- CSR build ----------------

__global__ void count_kernel(const int* __restrict__ ei, int* __restrict__ cnt) {
  int e = blockIdx.x * 256 + threadIdx.x;
  if (e >= EP) return;
  int dst = (e < N_EDGES) ? ei[N_EDGES + e] : (e - N_EDGES);
  atomicAdd(&cnt[dst], 1);
}

__global__ void scan_kernel(const int* __restrict__ cnt, int* __restrict__ off) {
  __shared__ int tmp[1024];
  __shared__ int carry_s;
  int tid = threadIdx.x;
  if (tid == 0) carry_s = 0;
  __syncthreads();
  for (int base = 0; base < N_NODES; base += 1024) {
    int i = base + tid;
    int v = (i < N_NODES) ? cnt[i] : 0;
    tmp[tid] = v;
    __syncthreads();
    for (int s = 1; s < 1024; s <<= 1) {
      int t = (tid >= s) ? tmp[tid - s] : 0;
      __syncthreads();
      tmp[tid] += t;
      __syncthreads();
    }
    int incl = tmp[tid];
    int total = tmp[1023];
    int carry = carry_s;
    if (i < N_NODES) off[i] = carry + incl - v;  // exclusive
    __syncthreads();
    if (tid == 0) carry_s = carry + total;
    __syncthreads();
  }
  if (tid == 0) off[N_NODES] = carry_s;
}

__global__ void scatter_kernel(const int* __restrict__ ei, const int* __restrict__ off,
                               int* __restrict__ cnt, int* __restrict__ esrc) {
  int e = blockIdx.x * 256 + threadIdx.x;
  if (e >= EP) return;
  int src, dst;
  if (e < N_EDGES) { src = ei[e]; dst = ei[N_EDGES + e]; }
  else { src = dst = e - N_EDGES; }
  int pos = off[dst] + atomicAdd(&cnt[dst], 1);
  esrc[pos] = src;
}

// ---------------- GEMM: [M,256] @ [256,256], fp32, 64x64 tile ----------------

__global__ __launch_bounds__(256) void gemm64(const float* __restrict__ A,
                                              const float* __restrict__ B,
                                              float* __restrict__ Cm, int M) {
  __shared__ float As[16][64];
  __shared__ float Bs[16][64];
  int tid = threadIdx.x;
  int bm = blockIdx.x * 64;
  int bn = blockIdx.y * 64;
  int lm  = tid >> 2;          // 0..63  A row in tile
  int lk4 = (tid & 3) * 4;     // A k quad
  int lbk = tid >> 4;          // 0..15  B k
  int lbn = (tid & 15) * 4;    // B col quad
  int rm = (tid >> 4) * 4;     // compute 4x4 micro-tile
  int cn = (tid & 15) * 4;
  float acc[4][4] = {};
  int arow = bm + lm;
  bool avalid = arow < M;
  const float* Aptr = A + (size_t)(avalid ? arow : 0) * 256;
  for (int k0 = 0; k0 < 256; k0 += 16) {
    float4 av = avalid ? *(const float4*)(Aptr + k0 + lk4) : make_float4(0.f, 0.f, 0.f, 0.f);
    float4 bv = *(const float4*)(B + (size_t)(k0 + lbk) * 256 + bn + lbn);
    __syncthreads();  // previous iteration's LDS reads complete before overwrite
    As[lk4 + 0][lm] = av.x; As[lk4 + 1][lm] = av.y;
    As[lk4 + 2][lm] = av.z; As[lk4 + 3][lm] = av.w;
    *(float4*)&Bs[lbk][lbn] = bv;
    __syncthreads();
#pragma unroll
    for (int kk = 0; kk < 16; ++kk) {
      float4 a4 = *(const float4*)&As[kk][rm];
      float4 b4 = *(const float4*)&Bs[kk][cn];
      float a_[4] = {a4.x, a4.y, a4.z, a4.w};
      float b_[4] = {b4.x, b4.y, b4.z, b4.w};
#pragma unroll
      for (int i = 0; i < 4; ++i)
#pragma unroll
        for (int j = 0; j < 4; ++j)
          acc[i][j] = fmaf(a_[i], b_[j], acc[i][j]);
    }
  }
#pragma unroll
  for (int i = 0; i < 4; ++i) {
    int row = bm + rm + i;
    if (row < M) {
      float4 o = make_float4(acc[i][0], acc[i][1], acc[i][2], acc[i][3]);
      *(float4*)(Cm + (size_t)row * 256 + bn + cn) = o;
    }
  }
}

// ---------------- layer-3 GEMM: [M,256] @ [256,10] ----------------

__global__ __launch_bounds__(256) void gemm_c_kernel(const float* __restrict__ X,
                                                     const float* __restrict__ W,
                                                     float* __restrict__ out) {
  __shared__ float Ws[256 * 10];
  __shared__ float Xs[16][256];
  int tid = threadIdx.x;
  int r0 = blockIdx.x * 16;
  for (int i = tid; i < 2560; i += 256) Ws[i] = W[i];
  for (int j = 0; j < 16; ++j) Xs[j][tid] = X[(size_t)(r0 + j) * 256 + tid];
  __syncthreads();
  if (tid < 160) {
    int row = tid / 10, col = tid % 10;
    float acc = 0.f;
#pragma unroll 8
    for (int k = 0; k < 256; ++k) acc = fmaf(Xs[row][k], Ws[k * 10 + col], acc);
    out[(size_t)(r0 + row) * 10 + col] = acc;
  }
}

// ---------------- alpha = h @ a_src, h @ a_dst (wave per row) ----------------

__global__ void alpha_kernel(const float* __restrict__ h, const float* __restrict__ asrc,
                             const float* __restrict__ adst, float* __restrict__ as_,
                             float* __restrict__ ad_, int D) {
  int gid = blockIdx.x * blockDim.x + threadIdx.x;
  int row = gid >> 6, lane = threadIdx.x & 63;
  if (row >= N_NODES) return;
  const float* hp = h + (size_t)row * D;
  float s = 0.f, d = 0.f;
  for (int k = lane; k < D; k += 64) { float v = hp[k]; s += v * asrc[k]; d += v * adst[k]; }
  for (int o = 32; o; o >>= 1) { s += __shfl_down(s, o); d += __shfl_down(d, o); }
  if (lane == 0) { as_[row] = s; ad_[row] = d; }
}

// ---------------- segment softmax (wave per dst) ----------------

__global__ void coeff_kernel(const int* __restrict__ off, const int* __restrict__ esrc,
                             const float* __restrict__ as_, const float* __restrict__ ad_,
                             float* __restrict__ coeff) {
  int gid = blockIdx.x * blockDim.x + threadIdx.x;
  int d = gid >> 6, lane = threadIdx.x & 63;
  if (d >= N_NODES) return;
  int s0 = off[d], s1 = off[d + 1];
  float adv = ad_[d];
  float m = -3.0e38f;
  for (int s = s0 + lane; s < s1; s += 64) {
    float e = as_[esrc[s]] + adv;
    e = e > 0.f ? e : NEG_SLOPE * e;
    m = fmaxf(m, e);
  }
  for (int o = 32; o; o >>= 1) m = fmaxf(m, __shfl_xor(m, o));
  float sum = 0.f;
  for (int s = s0 + lane; s < s1; s += 64) {
    float e = as_[esrc[s]] + adv;
    e = e > 0.f ? e : NEG_SLOPE * e;
    float p = __expf(e - m);
    coeff[s] = p;
    sum += p;
  }
  for (int o = 32; o; o >>= 1) sum += __shfl_xor(sum, o);
  float inv = 1.0f / sum;
  for (int s = s0 + lane; s < s1; s += 64) coeff[s] *= inv;
}

// ---------------- aggregation: out[d] = sum coeff * h[src] + b (+relu) ----------------

__global__ __launch_bounds__(256) void agg256_kernel(const int* __restrict__ off,
                                                     const int* __restrict__ esrc,
                                                     const float* __restrict__ coeff,
                                                     const float* __restrict__ h,
                                                     const float* __restrict__ bias,
                                                     float* __restrict__ out, int relu) {
  int d = blockIdx.x;
  int c = threadIdx.x;
  int s0 = off[d], s1 = off[d + 1];
  float acc = 0.f;
  for (int s = s0; s < s1; ++s) {
    float w = coeff[s];
    int src = esrc[s];
    acc = fmaf(w, h[(size_t)src * 256 + c], acc);
  }
  float o = acc + bias[c];
  if (relu) o = fmaxf(o, 0.f);
  out[(size_t)d * 256 + c] = o;
}

__global__ void agg10_kernel(const int* __restrict__ off, const int* __restrict__ esrc,
                             const float* __restrict__ coeff, const float* __restrict__ h,
                             const float* __restrict__ bias, float* __restrict__ out) {
  int gid = blockIdx.x * blockDim.x + threadIdx.x;
  int d = gid >> 6, lane = threadIdx.x & 63;
  if (d >= N_NODES) return;
  int s0 = off[d], s1 = off[d + 1];
  float acc = 0.f;
  for (int s = s0; s < s1; ++s) {
    float w = coeff[s];
    int src = esrc[s];
    if (lane < 10) acc = fmaf(w, h[(size_t)src * 10 + lane], acc);
  }
  if (lane < 10) out[(size_t)d * 10 + lane] = acc + bias[lane];
}

// ---------------- launch ----------------

extern "C" void kernel_launch(void* const* d_in, const int* in_sizes, int n_in,
                              void* d_out, int out_size, void* d_ws, size_t ws_size,
                              hipStream_t stream) {
  const float* x   = (const float*)d_in[0];
  const int*   ei  = (const int*)d_in[1];
  const float* W1  = (const float*)d_in[2];
  const float* as1 = (const float*)d_in[3];
  const float* ad1 = (const float*)d_in[4];
  const float* b1  = (const float*)d_in[5];
  const float* W2  = (const float*)d_in[6];
  const float* as2 = (const float*)d_in[7];
  const float* ad2 = (const float*)d_in[8];
  const float* b2  = (const float*)d_in[9];
  const float* W3  = (const float*)d_in[10];
  const float* as3 = (const float*)d_in[11];
  const float* ad3 = (const float*)d_in[12];
  const float* b3  = (const float*)d_in[13];
  float* out = (float*)d_out;

  char* ws = (char*)d_ws;
  size_t off_b = 0;
  auto alloc = [&](size_t bytes) -> char* {
    char* p = ws + off_b;
    off_b += (bytes + 255) & ~(size_t)255;
    return p;
  };
  float* h      = (float*)alloc((size_t)N_NODES * 256 * 4);
  float* g      = (float*)alloc((size_t)N_NODES * 256 * 4);
  float* h3     = (float*)alloc((size_t)N_NODES * 10 * 4);
  float* as_    = (float*)alloc((size_t)N_NODES * 4);
  float* ad_    = (float*)alloc((size_t)N_NODES * 4);
  int*   roff   = (int*)alloc((size_t)(N_NODES + 1) * 4);
  int*   cnt    = (int*)alloc((size_t)N_NODES * 4);
  int*   esrc   = (int*)alloc((size_t)EP * 4);
  float* coeff  = (float*)alloc((size_t)EP * 4);

  // CSR build (once; graph identical across the 3 layers)
  hipMemsetAsync(cnt, 0, N_NODES * 4, stream);
  int eb = (EP + 255) / 256;
  count_kernel<<<eb, 256, 0, stream>>>(ei, cnt);
  scan_kernel<<<1, 1024, 0, stream>>>(cnt, roff);
  hipMemsetAsync(cnt, 0, N_NODES * 4, stream);
  scatter_kernel<<<eb, 256, 0, stream>>>(ei, roff, cnt, esrc);

  dim3 ggrid((N_NODES + 63) / 64, 4);
  int wgrid = (N_NODES * 64 + 255) / 256;  // one wave per node

  // layer 1
  gemm64<<<ggrid, 256, 0, stream>>>(x, W1, h, N_NODES);
  alpha_kernel<<<wgrid, 256, 0, stream>>>(h, as1, ad1, as_, ad_, 256);
  coeff_kernel<<<wgrid, 256, 0, stream>>>(roff, esrc, as_, ad_, coeff);
  agg256_kernel<<<N_NODES, 256, 0, stream>>>(roff, esrc, coeff, h, b1, g, 1);
  // layer 2
  gemm64<<<ggrid, 256, 0, stream>>>(g, W2, h, N_NODES);
  alpha_kernel<<<wgrid, 256, 0, stream>>>(h, as2, ad2, as_, ad_, 256);
  coeff_kernel<<<wgrid, 256, 0, stream>>>(roff, esrc, as_, ad_, coeff);
  agg256_kernel<<<N_NODES, 256, 0, stream>>>(roff, esrc, coeff, h, b2, g, 1);
  // layer 3
  gemm_c_kernel<<<N_NODES / 16, 256, 0, stream>>>(g, W3, h3);
  alpha_kernel<<<wgrid, 256, 0, stream>>>(h3, as3, ad3, as_, ad_, 10);
  coeff_kernel<<<wgrid, 256, 0, stream>>>(roff, esrc, as_, ad_, coeff);
  agg10_kernel<<<wgrid, 256, 0, stream>>>(roff, esrc, coeff, h3, b3, out);
}

// Round 2
// 792.243 us; speedup vs baseline: 1.2580x; 1.2580x over previous
//
#include <hip/hip_runtime.h>
#include <math.h>

#define N_NODES 50000
#define N_EDGES 800000
#define EP (N_EDGES + N_NODES) /* 850000 edges incl self-loops */
#define NEG_SLOPE 0.2f

typedef short short8 __attribute__((ext_vector_type(8)));
typedef float float4_ __attribute__((ext_vector_type(4)));

__device__ __forceinline__ unsigned short f2bf(float f) {
  unsigned int u = __float_as_uint(f);
  u = (u + 0x7FFFu + ((u >> 16) & 1u)) >> 16;  // RNE
  return (unsigned short)u;
}
__device__ __forceinline__ float bf2f(unsigned int us) {
  return __uint_as_float(us << 16);
}

// ---------------- conversions ----------------

__global__ void cvt_x_kernel(const float* __restrict__ x, unsigned short* __restrict__ xb, int n4) {
  int i = blockIdx.x * 256 + threadIdx.x;
  if (i >= n4) return;
  float4 v = ((const float4*)x)[i];
  ushort4 o;
  o.x = f2bf(v.x); o.y = f2bf(v.y); o.z = f2bf(v.z); o.w = f2bf(v.w);
  ((ushort4*)xb)[i] = o;
}

// W [256][256] f32 row-major -> Wt [n][k] bf16
__global__ void cvt_wt_kernel(const float* __restrict__ W, unsigned short* __restrict__ Wt) {
  __shared__ unsigned short tile[32][33];
  int tx = threadIdx.x, ty = threadIdx.y;           // 32 x 8
  int k0 = blockIdx.x * 32, n0 = blockIdx.y * 32;
#pragma unroll
  for (int i = 0; i < 4; ++i)
    tile[ty + i * 8][tx] = f2bf(W[(size_t)(k0 + ty + i * 8) * 256 + n0 + tx]);
  __syncthreads();
#pragma unroll
  for (int i = 0; i < 4; ++i)
    Wt[(size_t)(n0 + ty + i * 8) * 256 + k0 + tx] = tile[tx][ty + i * 8];
}

// ---------------- CSR build ----------------

__global__ void count_kernel(const int* __restrict__ ei, int* __restrict__ cnt) {
  int e = blockIdx.x * 256 + threadIdx.x;
  if (e >= EP) return;
  int dst = (e < N_EDGES) ? ei[N_EDGES + e] : (e - N_EDGES);
  atomicAdd(&cnt[dst], 1);
}

__global__ void scan_kernel(const int* __restrict__ cnt, int* __restrict__ off) {
  __shared__ int tmp[1024];
  __shared__ int carry_s;
  int tid = threadIdx.x;
  if (tid == 0) carry_s = 0;
  __syncthreads();
  for (int base = 0; base < N_NODES; base += 1024) {
    int i = base + tid;
    int v = (i < N_NODES) ? cnt[i] : 0;
    tmp[tid] = v;
    __syncthreads();
    for (int s = 1; s < 1024; s <<= 1) {
      int t = (tid >= s) ? tmp[tid - s] : 0;
      __syncthreads();
      tmp[tid] += t;
      __syncthreads();
    }
    int incl = tmp[tid];
    int total = tmp[1023];
    int carry = carry_s;
    if (i < N_NODES) off[i] = carry + incl - v;  // exclusive
    __syncthreads();
    if (tid == 0) carry_s = carry + total;
    __syncthreads();
  }
  if (tid == 0) off[N_NODES] = carry_s;
}

__global__ void scatter_kernel(const int* __restrict__ ei, const int* __restrict__ off,
                               int* __restrict__ cnt, int* __restrict__ esrc) {
  int e = blockIdx.x * 256 + threadIdx.x;
  if (e >= EP) return;
  int src, dst;
  if (e < N_EDGES) { src = ei[e]; dst = ei[N_EDGES + e]; }
  else { src = dst = e - N_EDGES; }
  int pos = off[dst] + atomicAdd(&cnt[dst], 1);
  esrc[pos] = src;
}

// ---------------- bf16 MFMA GEMM: [M,256] @ Wt[256(n),256(k)] -> bf16 [M,256] ----------------
// Verified fragment layouts (learn_hip m89/m92): A-frag A[m=lane&15][k=(lane>>4)*8+j],
// B-frag from B^T rows (n=lane&15, same k packing), C/D col=lane&15 row=(lane>>4)*4+reg.

__global__ __launch_bounds__(256) void gemm_mfma(const unsigned short* __restrict__ A,
                                                 const unsigned short* __restrict__ Bt,
                                                 unsigned short* __restrict__ C, int M) {
  int tid = threadIdx.x;
  int wave = tid >> 6, lane = tid & 63;
  int lm = lane & 15, kg = lane >> 4;
  int row0 = blockIdx.x * 64 + wave * 16;
  int arow = row0 + lm;
  if (arow >= M) arow = M - 1;
  const unsigned short* aptr = A + (size_t)arow * 256 + kg * 8;
  const unsigned short* bptr = Bt + (size_t)lm * 256 + kg * 8;
  float4_ acc[16];
#pragma unroll
  for (int i = 0; i < 16; ++i) acc[i] = (float4_){0.f, 0.f, 0.f, 0.f};
  for (int k0 = 0; k0 < 256; k0 += 32) {
    short8 a = *(const short8*)(aptr + k0);
#pragma unroll
    for (int nt = 0; nt < 16; ++nt) {
      short8 b = *(const short8*)(bptr + k0 + nt * 4096);
      acc[nt] = __builtin_amdgcn_mfma_f32_16x16x32_bf16(a, b, acc[nt], 0, 0, 0);
    }
  }
  int r0 = row0 + kg * 4;
#pragma unroll
  for (int nt = 0; nt < 16; ++nt) {
    int c = nt * 16 + lm;
#pragma unroll
    for (int i = 0; i < 4; ++i) {
      int r = r0 + i;
      if (r < M) C[(size_t)r * 256 + c] = f2bf(acc[nt][i]);
    }
  }
}

// ---------------- layer-3 GEMM: bf16 [M,256] @ f32 [256,10] ----------------

__global__ __launch_bounds__(256) void gemm_c_kernel(const unsigned short* __restrict__ X,
                                                     const float* __restrict__ W,
                                                     float* __restrict__ out) {
  __shared__ float Ws[256 * 10];
  __shared__ float Xs[16][256];
  int tid = threadIdx.x;
  int r0 = blockIdx.x * 16;
  for (int i = tid; i < 2560; i += 256) Ws[i] = W[i];
  for (int j = 0; j < 16; ++j) Xs[j][tid] = bf2f(X[(size_t)(r0 + j) * 256 + tid]);
  __syncthreads();
  if (tid < 160) {
    int row = tid / 10, col = tid % 10;
    float acc = 0.f;
#pragma unroll 8
    for (int k = 0; k < 256; ++k) acc = fmaf(Xs[row][k], Ws[k * 10 + col], acc);
    out[(size_t)(r0 + row) * 10 + col] = acc;
  }
}

// ---------------- alpha = h @ a_src, h @ a_dst ----------------

__global__ void alpha_bf_kernel(const unsigned short* __restrict__ h, const float* __restrict__ asrc,
                                const float* __restrict__ adst, float* __restrict__ as_,
                                float* __restrict__ ad_) {
  int gid = blockIdx.x * blockDim.x + threadIdx.x;
  int row = gid >> 6, lane = threadIdx.x & 63;
  if (row >= N_NODES) return;
  const unsigned int* hp = (const unsigned int*)(h + (size_t)row * 256);
  float s = 0.f, d = 0.f;
#pragma unroll
  for (int k = lane; k < 128; k += 64) {
    unsigned int pv = hp[k];
    float v0 = bf2f(pv & 0xffffu), v1 = bf2f(pv >> 16);
    s += v0 * asrc[2 * k] + v1 * asrc[2 * k + 1];
    d += v0 * adst[2 * k] + v1 * adst[2 * k + 1];
  }
  for (int o = 32; o; o >>= 1) { s += __shfl_down(s, o); d += __shfl_down(d, o); }
  if (lane == 0) { as_[row] = s; ad_[row] = d; }
}

__global__ void alpha_f32_kernel(const float* __restrict__ h, const float* __restrict__ asrc,
                                 const float* __restrict__ adst, float* __restrict__ as_,
                                 float* __restrict__ ad_, int D) {
  int gid = blockIdx.x * blockDim.x + threadIdx.x;
  int row = gid >> 6, lane = threadIdx.x & 63;
  if (row >= N_NODES) return;
  const float* hp = h + (size_t)row * D;
  float s = 0.f, d = 0.f;
  for (int k = lane; k < D; k += 64) { float v = hp[k]; s += v * asrc[k]; d += v * adst[k]; }
  for (int o = 32; o; o >>= 1) { s += __shfl_down(s, o); d += __shfl_down(d, o); }
  if (lane == 0) { as_[row] = s; ad_[row] = d; }
}

// ---------------- segment softmax (wave per dst) ----------------

__global__ void coeff_kernel(const int* __restrict__ off, const int* __restrict__ esrc,
                             const float* __restrict__ as_, const float* __restrict__ ad_,
                             float* __restrict__ coeff) {
  int gid = blockIdx.x * blockDim.x + threadIdx.x;
  int d = gid >> 6, lane = threadIdx.x & 63;
  if (d >= N_NODES) return;
  int s0 = off[d], s1 = off[d + 1];
  float adv = ad_[d];
  float m = -3.0e38f;
  for (int s = s0 + lane; s < s1; s += 64) {
    float e = as_[esrc[s]] + adv;
    e = e > 0.f ? e : NEG_SLOPE * e;
    m = fmaxf(m, e);
  }
  for (int o = 32; o; o >>= 1) m = fmaxf(m, __shfl_xor(m, o));
  float sum = 0.f;
  for (int s = s0 + lane; s < s1; s += 64) {
    float e = as_[esrc[s]] + adv;
    e = e > 0.f ? e : NEG_SLOPE * e;
    float p = __expf(e - m);
    coeff[s] = p;
    sum += p;
  }
  for (int o = 32; o; o >>= 1) sum += __shfl_xor(sum, o);
  float inv = 1.0f / sum;
  for (int s = s0 + lane; s < s1; s += 64) coeff[s] *= inv;
}

// ---------------- aggregation (bf16 h): g[d] = relu(sum coeff*h[src] + b) -> bf16 ----------------

__global__ __launch_bounds__(128) void agg_bf_kernel(const int* __restrict__ off,
                                                     const int* __restrict__ esrc,
                                                     const float* __restrict__ coeff,
                                                     const unsigned short* __restrict__ h,
                                                     const float* __restrict__ bias,
                                                     unsigned short* __restrict__ outg) {
  int d = blockIdx.x;
  int t = threadIdx.x;  // 128 threads, 2 cols each (bf16x2 packed)
  int s0 = off[d], s1 = off[d + 1];
  const unsigned int* hp = (const unsigned int*)h;
  float a0 = 0.f, a1 = 0.f;
  for (int s = s0; s < s1; ++s) {
    float w = coeff[s];
    unsigned int pv = hp[(size_t)esrc[s] * 128 + t];
    a0 = fmaf(w, bf2f(pv & 0xffffu), a0);
    a1 = fmaf(w, bf2f(pv >> 16), a1);
  }
  float o0 = fmaxf(a0 + bias[2 * t], 0.f);
  float o1 = fmaxf(a1 + bias[2 * t + 1], 0.f);
  ((unsigned int*)outg)[(size_t)d * 128 + t] = (unsigned int)f2bf(o0) | ((unsigned int)f2bf(o1) << 16);
}

__global__ void agg10_kernel(const int* __restrict__ off, const int* __restrict__ esrc,
                             const float* __restrict__ coeff, const float* __restrict__ h,
                             const float* __restrict__ bias, float* __restrict__ out) {
  int gid = blockIdx.x * blockDim.x + threadIdx.x;
  int d = gid >> 6, lane = threadIdx.x & 63;
  if (d >= N_NODES) return;
  int s0 = off[d], s1 = off[d + 1];
  float acc = 0.f;
  for (int s = s0; s < s1; ++s) {
    float w = coeff[s];
    int src = esrc[s];
    if (lane < 10) acc = fmaf(w, h[(size_t)src * 10 + lane], acc);
  }
  if (lane < 10) out[(size_t)d * 10 + lane] = acc + bias[lane];
}

// ---------------- launch ----------------

extern "C" void kernel_launch(void* const* d_in, const int* in_sizes, int n_in,
                              void* d_out, int out_size, void* d_ws, size_t ws_size,
                              hipStream_t stream) {
  const float* x   = (const float*)d_in[0];
  const int*   ei  = (const int*)d_in[1];
  const float* W1  = (const float*)d_in[2];
  const float* as1 = (const float*)d_in[3];
  const float* ad1 = (const float*)d_in[4];
  const float* b1  = (const float*)d_in[5];
  const float* W2  = (const float*)d_in[6];
  const float* as2 = (const float*)d_in[7];
  const float* ad2 = (const float*)d_in[8];
  const float* b2  = (const float*)d_in[9];
  const float* W3  = (const float*)d_in[10];
  const float* as3 = (const float*)d_in[11];
  const float* ad3 = (const float*)d_in[12];
  const float* b3  = (const float*)d_in[13];
  float* out = (float*)d_out;

  char* ws = (char*)d_ws;
  size_t off_b = 0;
  auto alloc = [&](size_t bytes) -> char* {
    char* p = ws + off_b;
    off_b += (bytes + 255) & ~(size_t)255;
    return p;
  };
  unsigned short* xb   = (unsigned short*)alloc((size_t)N_NODES * 256 * 2);
  unsigned short* hb   = (unsigned short*)alloc((size_t)N_NODES * 256 * 2);
  unsigned short* gb   = (unsigned short*)alloc((size_t)N_NODES * 256 * 2);
  unsigned short* W1t  = (unsigned short*)alloc(256 * 256 * 2);
  unsigned short* W2t  = (unsigned short*)alloc(256 * 256 * 2);
  float* h3    = (float*)alloc((size_t)N_NODES * 10 * 4);
  float* as_   = (float*)alloc((size_t)N_NODES * 4);
  float* ad_   = (float*)alloc((size_t)N_NODES * 4);
  int*   roff  = (int*)alloc((size_t)(N_NODES + 1) * 4);
  int*   cnt   = (int*)alloc((size_t)N_NODES * 4);
  int*   esrc  = (int*)alloc((size_t)EP * 4);
  float* coeff = (float*)alloc((size_t)EP * 4);

  // conversions
  int n4 = N_NODES * 256 / 4;
  cvt_x_kernel<<<(n4 + 255) / 256, 256, 0, stream>>>(x, xb, n4);
  cvt_wt_kernel<<<dim3(8, 8), dim3(32, 8), 0, stream>>>(W1, W1t);
  cvt_wt_kernel<<<dim3(8, 8), dim3(32, 8), 0, stream>>>(W2, W2t);

  // CSR build (once; graph identical across the 3 layers)
  hipMemsetAsync(cnt, 0, N_NODES * 4, stream);
  int eb = (EP + 255) / 256;
  count_kernel<<<eb, 256, 0, stream>>>(ei, cnt);
  scan_kernel<<<1, 1024, 0, stream>>>(cnt, roff);
  hipMemsetAsync(cnt, 0, N_NODES * 4, stream);
  scatter_kernel<<<eb, 256, 0, stream>>>(ei, roff, cnt, esrc);

  int gblocks = (N_NODES + 63) / 64;
  int wgrid = (N_NODES * 64 + 255) / 256;  // one wave per node

  // layer 1
  gemm_mfma<<<gblocks, 256, 0, stream>>>(xb, W1t, hb, N_NODES);
  alpha_bf_kernel<<<wgrid, 256, 0, stream>>>(hb, as1, ad1, as_, ad_);
  coeff_kernel<<<wgrid, 256, 0, stream>>>(roff, esrc, as_, ad_, coeff);
  agg_bf_kernel<<<N_NODES, 128, 0, stream>>>(roff, esrc, coeff, hb, b1, gb);
  // layer 2
  gemm_mfma<<<gblocks, 256, 0, stream>>>(gb, W2t, hb, N_NODES);
  alpha_bf_kernel<<<wgrid, 256, 0, stream>>>(hb, as2, ad2, as_, ad_);
  coeff_kernel<<<wgrid, 256, 0, stream>>>(roff, esrc, as_, ad_, coeff);
  agg_bf_kernel<<<N_NODES, 128, 0, stream>>>(roff, esrc, coeff, hb, b2, gb);
  // layer 3
  gemm_c_kernel<<<N_NODES / 16, 256, 0, stream>>>(gb, W3, h3);
  alpha_f32_kernel<<<wgrid, 256, 0, stream>>>(h3, as3, ad3, as_, ad_, 10);
  coeff_kernel<<<wgrid, 256, 0, stream>>>(roff, esrc, as_, ad_, coeff);
  agg10_kernel<<<wgrid, 256, 0, stream>>>(roff, esrc, coeff, h3, b3, out);
}

// Round 3
// 520.149 us; speedup vs baseline: 1.9161x; 1.5231x over previous
//
#include <hip/hip_runtime.h>
#include <math.h>

#define N_NODES 50000
#define N_EDGES 800000
#define EP (N_EDGES + N_NODES) /* 850000 edges incl self-loops */
#define NEG_SLOPE 0.2f
#define SCAN_BLOCKS ((N_NODES + 255) / 256) /* 196 */

typedef short short8 __attribute__((ext_vector_type(8)));
typedef float float4_ __attribute__((ext_vector_type(4)));

__device__ __forceinline__ unsigned short f2bf(float f) {
  unsigned int u = __float_as_uint(f);
  u = (u + 0x7FFFu + ((u >> 16) & 1u)) >> 16;  // RNE
  return (unsigned short)u;
}
__device__ __forceinline__ float bf2f(unsigned int us) {
  return __uint_as_float(us << 16);
}

// ---------------- conversions ----------------

// W [256][256] f32 row-major -> Wt [n][k] bf16
__global__ void cvt_wt_kernel(const float* __restrict__ W, unsigned short* __restrict__ Wt) {
  __shared__ unsigned short tile[32][33];
  int tx = threadIdx.x, ty = threadIdx.y;           // 32 x 8
  int k0 = blockIdx.x * 32, n0 = blockIdx.y * 32;
#pragma unroll
  for (int i = 0; i < 4; ++i)
    tile[ty + i * 8][tx] = f2bf(W[(size_t)(k0 + ty + i * 8) * 256 + n0 + tx]);
  __syncthreads();
#pragma unroll
  for (int i = 0; i < 4; ++i)
    Wt[(size_t)(n0 + ty + i * 8) * 256 + k0 + tx] = tile[tx][ty + i * 8];
}

// ---------------- CSR build ----------------

__global__ void count_kernel(const int* __restrict__ ei, int* __restrict__ cnt) {
  int e = blockIdx.x * 256 + threadIdx.x;
  if (e >= EP) return;
  int dst = (e < N_EDGES) ? ei[N_EDGES + e] : (e - N_EDGES);
  atomicAdd(&cnt[dst], 1);
}

__global__ void scan1_kernel(const int* __restrict__ cnt, int* __restrict__ off,
                             int* __restrict__ bsum) {
  int i = blockIdx.x * 256 + threadIdx.x;
  int v = (i < N_NODES) ? cnt[i] : 0;
  int lane = threadIdx.x & 63, w = threadIdx.x >> 6;
  int x = v;
  for (int o = 1; o < 64; o <<= 1) { int y = __shfl_up(x, o); if (lane >= o) x += y; }
  __shared__ int wsum[4];
  if (lane == 63) wsum[w] = x;
  __syncthreads();
  int add = 0;
  for (int k = 0; k < w; ++k) add += wsum[k];
  if (i < N_NODES) off[i] = x - v + add;  // block-local exclusive
  if (threadIdx.x == 255) bsum[blockIdx.x] = add + x;
}

__global__ void scan2_kernel(int* __restrict__ bsum, int* __restrict__ bpre,
                             int* __restrict__ off) {
  int t = threadIdx.x;
  int v = (t < SCAN_BLOCKS) ? bsum[t] : 0;
  int lane = t & 63, w = t >> 6;
  int x = v;
  for (int o = 1; o < 64; o <<= 1) { int y = __shfl_up(x, o); if (lane >= o) x += y; }
  __shared__ int wsum[4];
  if (lane == 63) wsum[w] = x;
  __syncthreads();
  int add = 0;
  for (int k = 0; k < w; ++k) add += wsum[k];
  if (t < SCAN_BLOCKS) bpre[t] = x - v + add;
  if (t == 255) off[N_NODES] = add + x;  // grand total == EP
}

__global__ void scan3_kernel(int* __restrict__ off, const int* __restrict__ bpre) {
  int i = blockIdx.x * 256 + threadIdx.x;
  if (i < N_NODES) off[i] += bpre[blockIdx.x];
}

__global__ void scatter_kernel(const int* __restrict__ ei, const int* __restrict__ off,
                               int* __restrict__ cnt, int* __restrict__ esrc) {
  int e = blockIdx.x * 256 + threadIdx.x;
  if (e >= EP) return;
  int src, dst;
  if (e < N_EDGES) { src = ei[e]; dst = ei[N_EDGES + e]; }
  else { src = dst = e - N_EDGES; }
  int pos = off[dst] + atomicAdd(&cnt[dst], 1);
  esrc[pos] = src;
}

// ---- bf16 MFMA GEMM + fused alpha: [M,256] @ Wt[n][k] -> bf16 [M,256], as_, ad_ ----
// Fragment layouts (learn_hip m89/m92): A-frag A[m=lane&15][k=(lane>>4)*8+j],
// B-frag = rows of B^T, C/D col=lane&15 row=(lane>>4)*4+reg.
// Each wave computes 32 rows (2 row-groups share every B fragment -> half B traffic).

template <int AF32>
__global__ __launch_bounds__(256) void gemm_mfma2(const void* __restrict__ Av,
                                                  const unsigned short* __restrict__ Bt,
                                                  unsigned short* __restrict__ C,
                                                  const float* __restrict__ asrc,
                                                  const float* __restrict__ adst,
                                                  float* __restrict__ as_,
                                                  float* __restrict__ ad_, int M) {
  int tid = threadIdx.x;
  int wave = tid >> 6, lane = tid & 63;
  int lm = lane & 15, kg = lane >> 4;
  int row0 = blockIdx.x * 128 + wave * 32;
  int ar0 = row0 + lm, ar1 = row0 + 16 + lm;
  if (ar0 >= M) ar0 = M - 1;
  if (ar1 >= M) ar1 = M - 1;
  float4_ acc0[16], acc1[16];
#pragma unroll
  for (int i = 0; i < 16; ++i) { acc0[i] = (float4_){0, 0, 0, 0}; acc1[i] = (float4_){0, 0, 0, 0}; }
  const unsigned short* bptr = Bt + (size_t)lm * 256 + kg * 8;
  for (int k0 = 0; k0 < 256; k0 += 32) {
    short8 a0, a1;
    if (AF32) {
      const float* A = (const float*)Av;
      const float* p0 = A + (size_t)ar0 * 256 + kg * 8 + k0;
      const float* p1 = A + (size_t)ar1 * 256 + kg * 8 + k0;
      float4 f0 = *(const float4*)p0, f1 = *(const float4*)(p0 + 4);
      float4 g0 = *(const float4*)p1, g1 = *(const float4*)(p1 + 4);
      a0 = (short8){(short)f2bf(f0.x), (short)f2bf(f0.y), (short)f2bf(f0.z), (short)f2bf(f0.w),
                    (short)f2bf(f1.x), (short)f2bf(f1.y), (short)f2bf(f1.z), (short)f2bf(f1.w)};
      a1 = (short8){(short)f2bf(g0.x), (short)f2bf(g0.y), (short)f2bf(g0.z), (short)f2bf(g0.w),
                    (short)f2bf(g1.x), (short)f2bf(g1.y), (short)f2bf(g1.z), (short)f2bf(g1.w)};
    } else {
      const unsigned short* A = (const unsigned short*)Av;
      a0 = *(const short8*)(A + (size_t)ar0 * 256 + kg * 8 + k0);
      a1 = *(const short8*)(A + (size_t)ar1 * 256 + kg * 8 + k0);
    }
#pragma unroll
    for (int nt = 0; nt < 16; ++nt) {
      short8 b = *(const short8*)(bptr + k0 + nt * 4096);
      acc0[nt] = __builtin_amdgcn_mfma_f32_16x16x32_bf16(a0, b, acc0[nt], 0, 0, 0);
      acc1[nt] = __builtin_amdgcn_mfma_f32_16x16x32_bf16(a1, b, acc1[nt], 0, 0, 0);
    }
  }
  // epilogue: store C + fused alpha (computed from fp32 acc)
  float avs[16], avd[16];
#pragma unroll
  for (int nt = 0; nt < 16; ++nt) { avs[nt] = asrc[nt * 16 + lm]; avd[nt] = adst[nt * 16 + lm]; }
#pragma unroll
  for (int g = 0; g < 2; ++g) {
    int rbase = row0 + g * 16 + kg * 4;
#pragma unroll
    for (int i = 0; i < 4; ++i) {
      int r = rbase + i;
      float s = 0.f, dd = 0.f;
#pragma unroll
      for (int nt = 0; nt < 16; ++nt) {
        float v = g ? acc1[nt][i] : acc0[nt][i];
        if (r < M) C[(size_t)r * 256 + nt * 16 + lm] = f2bf(v);
        s += v * avs[nt];
        dd += v * avd[nt];
      }
#pragma unroll
      for (int o = 1; o < 16; o <<= 1) { s += __shfl_xor(s, o); dd += __shfl_xor(dd, o); }
      if (lm == 0 && r < M) { as_[r] = s; ad_[r] = dd; }
    }
  }
}

// ---------------- layer-3 GEMM + fused alpha: bf16 [M,256] @ f32 [256,10] ----------------

__global__ __launch_bounds__(256) void gemm_c_kernel(const unsigned short* __restrict__ X,
                                                     const float* __restrict__ W,
                                                     const float* __restrict__ asrc,
                                                     const float* __restrict__ adst,
                                                     float* __restrict__ out,
                                                     float* __restrict__ as_,
                                                     float* __restrict__ ad_) {
  __shared__ float Ws[256 * 10];
  __shared__ float Xs[16][256];
  __shared__ float Os[16][10];
  int tid = threadIdx.x;
  int r0 = blockIdx.x * 16;
  for (int i = tid; i < 2560; i += 256) Ws[i] = W[i];
  for (int j = 0; j < 16; ++j) Xs[j][tid] = bf2f(X[(size_t)(r0 + j) * 256 + tid]);
  __syncthreads();
  if (tid < 160) {
    int row = tid / 10, col = tid % 10;
    float acc = 0.f;
#pragma unroll 8
    for (int k = 0; k < 256; ++k) acc = fmaf(Xs[row][k], Ws[k * 10 + col], acc);
    out[(size_t)(r0 + row) * 10 + col] = acc;
    Os[row][col] = acc;
  }
  __syncthreads();
  if (tid < 16) {
    float s = 0.f, dd = 0.f;
#pragma unroll
    for (int c = 0; c < 10; ++c) { float v = Os[tid][c]; s += v * asrc[c]; dd += v * adst[c]; }
    as_[r0 + tid] = s;
    ad_[r0 + tid] = dd;
  }
}

// ---------------- segment softmax (wave per dst, e cached in coeff[]) ----------------

__global__ void coeff_kernel(const int* __restrict__ off, const int* __restrict__ esrc,
                             const float* __restrict__ as_, const float* __restrict__ ad_,
                             float* __restrict__ coeff) {
  int gid = blockIdx.x * blockDim.x + threadIdx.x;
  int d = gid >> 6, lane = threadIdx.x & 63;
  if (d >= N_NODES) return;
  int s0 = off[d], s1 = off[d + 1];
  float adv = ad_[d];
  float m = -3.0e38f;
  for (int s = s0 + lane; s < s1; s += 64) {
    float e = as_[esrc[s]] + adv;
    e = e > 0.f ? e : NEG_SLOPE * e;
    coeff[s] = e;
    m = fmaxf(m, e);
  }
  for (int o = 32; o; o >>= 1) m = fmaxf(m, __shfl_xor(m, o));
  float sum = 0.f;
  for (int s = s0 + lane; s < s1; s += 64) {
    float p = __expf(coeff[s] - m);
    coeff[s] = p;
    sum += p;
  }
  for (int o = 32; o; o >>= 1) sum += __shfl_xor(sum, o);
  float inv = 1.0f / sum;
  for (int s = s0 + lane; s < s1; s += 64) coeff[s] *= inv;
}

// ---------------- aggregation (bf16 h): g[d] = relu(sum coeff*h[src] + b) -> bf16 ----------------
// LDS-staged edge list (coalesced, read-once) + 4x unrolled gathers for MLP.

__global__ __launch_bounds__(128) void agg_bf_kernel(const int* __restrict__ off,
                                                     const int* __restrict__ esrc,
                                                     const float* __restrict__ coeff,
                                                     const unsigned short* __restrict__ h,
                                                     const float* __restrict__ bias,
                                                     unsigned short* __restrict__ outg) {
  __shared__ int s_src[256];
  __shared__ float s_w[256];
  int d = blockIdx.x;
  int t = threadIdx.x;  // 128 threads, 2 cols each (bf16x2 packed)
  int s0 = off[d], s1 = off[d + 1];
  const unsigned int* hp = (const unsigned int*)h;
  float a0 = 0.f, a1 = 0.f;
  for (int base = s0; base < s1; base += 256) {
    int m = s1 - base; if (m > 256) m = 256;
    if (t < m) { s_src[t] = esrc[base + t]; s_w[t] = coeff[base + t]; }
    if (t + 128 < m) { s_src[t + 128] = esrc[base + t + 128]; s_w[t + 128] = coeff[base + t + 128]; }
    __syncthreads();
    int j = 0;
    for (; j + 4 <= m; j += 4) {
      int i0 = s_src[j], i1 = s_src[j + 1], i2 = s_src[j + 2], i3 = s_src[j + 3];
      float w0 = s_w[j], w1 = s_w[j + 1], w2 = s_w[j + 2], w3 = s_w[j + 3];
      unsigned int p0 = hp[(size_t)i0 * 128 + t];
      unsigned int p1 = hp[(size_t)i1 * 128 + t];
      unsigned int p2 = hp[(size_t)i2 * 128 + t];
      unsigned int p3 = hp[(size_t)i3 * 128 + t];
      a0 = fmaf(w0, bf2f(p0 & 0xffffu), a0); a1 = fmaf(w0, bf2f(p0 >> 16), a1);
      a0 = fmaf(w1, bf2f(p1 & 0xffffu), a0); a1 = fmaf(w1, bf2f(p1 >> 16), a1);
      a0 = fmaf(w2, bf2f(p2 & 0xffffu), a0); a1 = fmaf(w2, bf2f(p2 >> 16), a1);
      a0 = fmaf(w3, bf2f(p3 & 0xffffu), a0); a1 = fmaf(w3, bf2f(p3 >> 16), a1);
    }
    for (; j < m; ++j) {
      float w = s_w[j];
      unsigned int pv = hp[(size_t)s_src[j] * 128 + t];
      a0 = fmaf(w, bf2f(pv & 0xffffu), a0);
      a1 = fmaf(w, bf2f(pv >> 16), a1);
    }
    __syncthreads();
  }
  float o0 = fmaxf(a0 + bias[2 * t], 0.f);
  float o1 = fmaxf(a1 + bias[2 * t + 1], 0.f);
  ((unsigned int*)outg)[(size_t)d * 128 + t] = (unsigned int)f2bf(o0) | ((unsigned int)f2bf(o1) << 16);
}

// ---------------- final aggregation, D=10 (4 dsts per wave) ----------------

__global__ void agg10_kernel(const int* __restrict__ off, const int* __restrict__ esrc,
                             const float* __restrict__ coeff, const float* __restrict__ h,
                             const float* __restrict__ bias, float* __restrict__ out) {
  int gid = blockIdx.x * blockDim.x + threadIdx.x;
  int wid = gid >> 6;
  int lane = threadIdx.x & 63;
  int sub = lane >> 4, c = lane & 15;
  int d = wid * 4 + sub;
  if (d >= N_NODES || c >= 10) return;
  int s0 = off[d], s1 = off[d + 1];
  float acc = 0.f;
  for (int s = s0; s < s1; ++s)
    acc = fmaf(coeff[s], h[(size_t)esrc[s] * 10 + c], acc);
  out[(size_t)d * 10 + c] = acc + bias[c];
}

// ---------------- launch ----------------

extern "C" void kernel_launch(void* const* d_in, const int* in_sizes, int n_in,
                              void* d_out, int out_size, void* d_ws, size_t ws_size,
                              hipStream_t stream) {
  const float* x   = (const float*)d_in[0];
  const int*   ei  = (const int*)d_in[1];
  const float* W1  = (const float*)d_in[2];
  const float* as1 = (const float*)d_in[3];
  const float* ad1 = (const float*)d_in[4];
  const float* b1  = (const float*)d_in[5];
  const float* W2  = (const float*)d_in[6];
  const float* as2 = (const float*)d_in[7];
  const float* ad2 = (const float*)d_in[8];
  const float* b2  = (const float*)d_in[9];
  const float* W3  = (const float*)d_in[10];
  const float* as3 = (const float*)d_in[11];
  const float* ad3 = (const float*)d_in[12];
  const float* b3  = (const float*)d_in[13];
  float* out = (float*)d_out;

  char* ws = (char*)d_ws;
  size_t off_b = 0;
  auto alloc = [&](size_t bytes) -> char* {
    char* p = ws + off_b;
    off_b += (bytes + 255) & ~(size_t)255;
    return p;
  };
  unsigned short* hb   = (unsigned short*)alloc((size_t)N_NODES * 256 * 2);
  unsigned short* gb   = (unsigned short*)alloc((size_t)N_NODES * 256 * 2);
  unsigned short* W1t  = (unsigned short*)alloc(256 * 256 * 2);
  unsigned short* W2t  = (unsigned short*)alloc(256 * 256 * 2);
  float* h3    = (float*)alloc((size_t)N_NODES * 10 * 4);
  float* as_   = (float*)alloc((size_t)N_NODES * 4);
  float* ad_   = (float*)alloc((size_t)N_NODES * 4);
  int*   roff  = (int*)alloc((size_t)(N_NODES + 1) * 4);
  int*   cnt   = (int*)alloc((size_t)N_NODES * 4);
  int*   bsum  = (int*)alloc((size_t)SCAN_BLOCKS * 4);
  int*   bpre  = (int*)alloc((size_t)SCAN_BLOCKS * 4);
  int*   esrc  = (int*)alloc((size_t)EP * 4);
  float* coeff = (float*)alloc((size_t)EP * 4);

  cvt_wt_kernel<<<dim3(8, 8), dim3(32, 8), 0, stream>>>(W1, W1t);
  cvt_wt_kernel<<<dim3(8, 8), dim3(32, 8), 0, stream>>>(W2, W2t);

  // CSR build (once; graph identical across the 3 layers)
  hipMemsetAsync(cnt, 0, N_NODES * 4, stream);
  int eb = (EP + 255) / 256;
  count_kernel<<<eb, 256, 0, stream>>>(ei, cnt);
  scan1_kernel<<<SCAN_BLOCKS, 256, 0, stream>>>(cnt, roff, bsum);
  scan2_kernel<<<1, 256, 0, stream>>>(bsum, bpre, roff);
  scan3_kernel<<<SCAN_BLOCKS, 256, 0, stream>>>(roff, bpre);
  hipMemsetAsync(cnt, 0, N_NODES * 4, stream);
  scatter_kernel<<<eb, 256, 0, stream>>>(ei, roff, cnt, esrc);

  int gblocks = (N_NODES + 127) / 128;
  int wgrid = (N_NODES * 64 + 255) / 256;    // one wave per node
  int wgrid4 = (N_NODES * 16 + 255) / 256;   // 4 dsts per wave

  // layer 1 (A = x in f32; alpha fused into gemm)
  gemm_mfma2<1><<<gblocks, 256, 0, stream>>>(x, W1t, hb, as1, ad1, as_, ad_, N_NODES);
  coeff_kernel<<<wgrid, 256, 0, stream>>>(roff, esrc, as_, ad_, coeff);
  agg_bf_kernel<<<N_NODES, 128, 0, stream>>>(roff, esrc, coeff, hb, b1, gb);
  // layer 2
  gemm_mfma2<0><<<gblocks, 256, 0, stream>>>(gb, W2t, hb, as2, ad2, as_, ad_, N_NODES);
  coeff_kernel<<<wgrid, 256, 0, stream>>>(roff, esrc, as_, ad_, coeff);
  agg_bf_kernel<<<N_NODES, 128, 0, stream>>>(roff, esrc, coeff, hb, b2, gb);
  // layer 3 (alpha fused into gemm_c)
  gemm_c_kernel<<<N_NODES / 16, 256, 0, stream>>>(gb, W3, as3, ad3, h3, as_, ad_);
  coeff_kernel<<<wgrid, 256, 0, stream>>>(roff, esrc, as_, ad_, coeff);
  agg10_kernel<<<wgrid4, 256, 0, stream>>>(roff, esrc, coeff, h3, b3, out);
}

// Round 4
// 428.273 us; speedup vs baseline: 2.3272x; 1.2145x over previous
//
#include <hip/hip_runtime.h>
#include <math.h>

#define N_NODES 50000
#define N_EDGES 800000
#define EP (N_EDGES + N_NODES) /* 850000 edges incl self-loops */
#define NEG_SLOPE 0.2f
#define SCAN_BLOCKS ((N_NODES + 255) / 256) /* 196 */

typedef short short8 __attribute__((ext_vector_type(8)));
typedef float float4_ __attribute__((ext_vector_type(4)));

__device__ __forceinline__ unsigned short f2bf(float f) {
  unsigned int u = __float_as_uint(f);
  u = (u + 0x7FFFu + ((u >> 16) & 1u)) >> 16;  // RNE
  return (unsigned short)u;
}
__device__ __forceinline__ float bf2f(unsigned int us) {
  return __uint_as_float(us << 16);
}

// ---------------- conversions: W [256][256] f32 -> fragment-major bf16 ----------------
// Wf[((nt*8 + k0t)*64 + lane)*8 + j] = bf16(W[(k0t*32 + kg*8 + j)*256 + nt*16 + lm])
// where lane = kg*16 + lm. This makes gemm LDS staging a pure linear copy and every
// B-fragment read a conflict-free ds_read_b128.

__global__ void cvt_wf_kernel(const float* __restrict__ W, unsigned short* __restrict__ Wf) {
  int t = blockIdx.x * 256 + threadIdx.x;  // 8192 threads
  int f = t >> 6, lane = t & 63;
  int nt = f >> 3, k0t = f & 7;
  int lm = lane & 15, kg = lane >> 4;
  int kbase = k0t * 32 + kg * 8;
  int n = nt * 16 + lm;
  short8 v;
#pragma unroll
  for (int j = 0; j < 8; ++j) v[j] = (short)f2bf(W[(size_t)(kbase + j) * 256 + n]);
  ((short8*)Wf)[t] = v;
}

// W3 [256][10] f32 -> 8 fragments (nt=0 only, cols padded to 16 with zeros)
__global__ void cvt_wf3_kernel(const float* __restrict__ W3, unsigned short* __restrict__ Wf3) {
  int t = blockIdx.x * 256 + threadIdx.x;  // 512 threads
  int k0t = t >> 6, lane = t & 63;
  int lm = lane & 15, kg = lane >> 4;
  int kbase = k0t * 32 + kg * 8;
  short8 v;
#pragma unroll
  for (int j = 0; j < 8; ++j)
    v[j] = (lm < 10) ? (short)f2bf(W3[(size_t)(kbase + j) * 10 + lm]) : (short)0;
  ((short8*)Wf3)[t] = v;
}

// ---------------- CSR build ----------------

__global__ void count_kernel(const int* __restrict__ ei, int* __restrict__ cnt) {
  int e = blockIdx.x * 256 + threadIdx.x;
  if (e >= EP) return;
  int dst = (e < N_EDGES) ? ei[N_EDGES + e] : (e - N_EDGES);
  atomicAdd(&cnt[dst], 1);
}

__global__ void scan1_kernel(const int* __restrict__ cnt, int* __restrict__ off,
                             int* __restrict__ bsum) {
  int i = blockIdx.x * 256 + threadIdx.x;
  int v = (i < N_NODES) ? cnt[i] : 0;
  int lane = threadIdx.x & 63, w = threadIdx.x >> 6;
  int x = v;
  for (int o = 1; o < 64; o <<= 1) { int y = __shfl_up(x, o); if (lane >= o) x += y; }
  __shared__ int wsum[4];
  if (lane == 63) wsum[w] = x;
  __syncthreads();
  int add = 0;
  for (int k = 0; k < w; ++k) add += wsum[k];
  if (i < N_NODES) off[i] = x - v + add;  // block-local exclusive
  if (threadIdx.x == 255) bsum[blockIdx.x] = add + x;
}

__global__ void scan2_kernel(int* __restrict__ bsum, int* __restrict__ bpre,
                             int* __restrict__ off) {
  int t = threadIdx.x;
  int v = (t < SCAN_BLOCKS) ? bsum[t] : 0;
  int lane = t & 63, w = t >> 6;
  int x = v;
  for (int o = 1; o < 64; o <<= 1) { int y = __shfl_up(x, o); if (lane >= o) x += y; }
  __shared__ int wsum[4];
  if (lane == 63) wsum[w] = x;
  __syncthreads();
  int add = 0;
  for (int k = 0; k < w; ++k) add += wsum[k];
  if (t < SCAN_BLOCKS) bpre[t] = x - v + add;
  if (t == 255) off[N_NODES] = add + x;  // grand total == EP
}

__global__ void scan3_kernel(int* __restrict__ off, const int* __restrict__ bpre) {
  int i = blockIdx.x * 256 + threadIdx.x;
  if (i < N_NODES) off[i] += bpre[blockIdx.x];
}

__global__ void scatter_kernel(const int* __restrict__ ei, const int* __restrict__ off,
                               int* __restrict__ cnt, int* __restrict__ esrc) {
  int e = blockIdx.x * 256 + threadIdx.x;
  if (e >= EP) return;
  int src, dst;
  if (e < N_EDGES) { src = ei[e]; dst = ei[N_EDGES + e]; }
  else { src = dst = e - N_EDGES; }
  int pos = off[dst] + atomicAdd(&cnt[dst], 1);
  esrc[pos] = src;
}

// ---- bf16 MFMA GEMM, B staged in LDS (fragment-major, 128 KB) + fused alpha ----
// Wave computes 32 rows (2 row-groups share each B fragment). Block = 128 rows.

template <int AF32>
__global__ __launch_bounds__(256, 1) void gemm_mfma3(const void* __restrict__ Av,
                                                     const uint4* __restrict__ Wf,
                                                     unsigned short* __restrict__ C,
                                                     const float* __restrict__ asrc,
                                                     const float* __restrict__ adst,
                                                     float* __restrict__ as_,
                                                     float* __restrict__ ad_, int M) {
  __shared__ uint4 Bl[8192];  // 128 KB
  int tid = threadIdx.x;
#pragma unroll
  for (int i = 0; i < 32; ++i) Bl[i * 256 + tid] = Wf[i * 256 + tid];
  int wave = tid >> 6, lane = tid & 63;
  int lm = lane & 15, kg = lane >> 4;
  int row0 = blockIdx.x * 128 + wave * 32;
  int ar0 = row0 + lm, ar1 = row0 + 16 + lm;
  if (ar0 >= M) ar0 = M - 1;
  if (ar1 >= M) ar1 = M - 1;
  float4_ acc0[16], acc1[16];
#pragma unroll
  for (int i = 0; i < 16; ++i) { acc0[i] = (float4_){0, 0, 0, 0}; acc1[i] = (float4_){0, 0, 0, 0}; }
  __syncthreads();
  const short8* Bf = (const short8*)Bl;
  for (int k0t = 0; k0t < 8; ++k0t) {
    int k0 = k0t * 32;
    short8 a0, a1;
    if (AF32) {
      const float* A = (const float*)Av;
      const float* p0 = A + (size_t)ar0 * 256 + kg * 8 + k0;
      const float* p1 = A + (size_t)ar1 * 256 + kg * 8 + k0;
      float4 f0 = *(const float4*)p0, f1 = *(const float4*)(p0 + 4);
      float4 g0 = *(const float4*)p1, g1 = *(const float4*)(p1 + 4);
      a0 = (short8){(short)f2bf(f0.x), (short)f2bf(f0.y), (short)f2bf(f0.z), (short)f2bf(f0.w),
                    (short)f2bf(f1.x), (short)f2bf(f1.y), (short)f2bf(f1.z), (short)f2bf(f1.w)};
      a1 = (short8){(short)f2bf(g0.x), (short)f2bf(g0.y), (short)f2bf(g0.z), (short)f2bf(g0.w),
                    (short)f2bf(g1.x), (short)f2bf(g1.y), (short)f2bf(g1.z), (short)f2bf(g1.w)};
    } else {
      const unsigned short* A = (const unsigned short*)Av;
      a0 = *(const short8*)(A + (size_t)ar0 * 256 + kg * 8 + k0);
      a1 = *(const short8*)(A + (size_t)ar1 * 256 + kg * 8 + k0);
    }
#pragma unroll
    for (int nt = 0; nt < 16; ++nt) {
      short8 b = Bf[(nt * 8 + k0t) * 64 + lane];
      acc0[nt] = __builtin_amdgcn_mfma_f32_16x16x32_bf16(a0, b, acc0[nt], 0, 0, 0);
      acc1[nt] = __builtin_amdgcn_mfma_f32_16x16x32_bf16(a1, b, acc1[nt], 0, 0, 0);
    }
  }
  // epilogue: store C + fused alpha (from fp32 acc)
  float avs[16], avd[16];
#pragma unroll
  for (int nt = 0; nt < 16; ++nt) { avs[nt] = asrc[nt * 16 + lm]; avd[nt] = adst[nt * 16 + lm]; }
#pragma unroll
  for (int g = 0; g < 2; ++g) {
    int rbase = row0 + g * 16 + kg * 4;
#pragma unroll
    for (int i = 0; i < 4; ++i) {
      int r = rbase + i;
      float s = 0.f, dd = 0.f;
#pragma unroll
      for (int nt = 0; nt < 16; ++nt) {
        float v = g ? acc1[nt][i] : acc0[nt][i];
        if (r < M) C[(size_t)r * 256 + nt * 16 + lm] = f2bf(v);
        s += v * avs[nt];
        dd += v * avd[nt];
      }
#pragma unroll
      for (int o = 1; o < 16; o <<= 1) { s += __shfl_xor(s, o); dd += __shfl_xor(dd, o); }
      if (lm == 0 && r < M) { as_[r] = s; ad_[r] = dd; }
    }
  }
}

// ---- layer-3 MFMA GEMM: bf16 [M,256] @ Wf3 (cols 0..9, padded 16) + fused alpha ----

__global__ __launch_bounds__(256) void gemm_c3_kernel(const unsigned short* __restrict__ X,
                                                      const unsigned short* __restrict__ Wf3,
                                                      const float* __restrict__ asrc,
                                                      const float* __restrict__ adst,
                                                      float* __restrict__ h3,
                                                      float* __restrict__ as_,
                                                      float* __restrict__ ad_, int M) {
  int tid = threadIdx.x;
  int wave = tid >> 6, lane = tid & 63;
  int lm = lane & 15, kg = lane >> 4;
  int row0 = blockIdx.x * 128 + wave * 32;
  int ar0 = row0 + lm, ar1 = row0 + 16 + lm;
  if (ar0 >= M) ar0 = M - 1;
  if (ar1 >= M) ar1 = M - 1;
  short8 bf[8];
#pragma unroll
  for (int k0t = 0; k0t < 8; ++k0t) bf[k0t] = ((const short8*)Wf3)[k0t * 64 + lane];
  float4_ acc0 = (float4_){0, 0, 0, 0}, acc1 = (float4_){0, 0, 0, 0};
#pragma unroll
  for (int k0t = 0; k0t < 8; ++k0t) {
    int k0 = k0t * 32;
    short8 a0 = *(const short8*)(X + (size_t)ar0 * 256 + kg * 8 + k0);
    short8 a1 = *(const short8*)(X + (size_t)ar1 * 256 + kg * 8 + k0);
    acc0 = __builtin_amdgcn_mfma_f32_16x16x32_bf16(a0, bf[k0t], acc0, 0, 0, 0);
    acc1 = __builtin_amdgcn_mfma_f32_16x16x32_bf16(a1, bf[k0t], acc1, 0, 0, 0);
  }
  float avs = (lm < 10) ? asrc[lm] : 0.f;
  float avd = (lm < 10) ? adst[lm] : 0.f;
#pragma unroll
  for (int g = 0; g < 2; ++g) {
    int rbase = row0 + g * 16 + kg * 4;
#pragma unroll
    for (int i = 0; i < 4; ++i) {
      int r = rbase + i;
      float v = g ? acc1[i] : acc0[i];
      if (r < M && lm < 10) h3[(size_t)r * 10 + lm] = v;
      float s = v * avs, dd = v * avd;
#pragma unroll
      for (int o = 1; o < 16; o <<= 1) { s += __shfl_xor(s, o); dd += __shfl_xor(dd, o); }
      if (lm == 0 && r < M) { as_[r] = s; ad_[r] = dd; }
    }
  }
}

// ---- fused softmax + aggregation (layers 1&2): one wave per dst ----
// p = exp(leaky(as_[src]+ad_[d])) without max-subtraction (|e| << 88, f32-safe);
// accumulate raw sum(p*h) and sum(p); scale by 1/sum at the end. No coeff[] traffic.

__global__ __launch_bounds__(256) void agg_fused_kernel(const int* __restrict__ off,
                                                        const int* __restrict__ esrc,
                                                        const float* __restrict__ as_,
                                                        const float* __restrict__ ad_,
                                                        const unsigned short* __restrict__ h,
                                                        const float* __restrict__ bias,
                                                        unsigned short* __restrict__ outg) {
  __shared__ int s_src[4][64];
  __shared__ float s_p[4][64];
  int wave = threadIdx.x >> 6, lane = threadIdx.x & 63;
  int d = blockIdx.x * 4 + wave;
  if (d >= N_NODES) return;
  int s0 = off[d], s1 = off[d + 1];
  float adv = ad_[d];
  const uint2* hp = (const uint2*)h;  // lane covers cols [4*lane, 4*lane+4)
  float a0 = 0.f, a1 = 0.f, a2 = 0.f, a3 = 0.f;
  float sum = 0.f;
  for (int base = s0; base < s1; base += 64) {
    int m = s1 - base; if (m > 64) m = 64;
    int sv = 0; float p = 0.f;
    if (lane < m) {
      sv = esrc[base + lane];
      float e = as_[sv] + adv;
      e = e > 0.f ? e : NEG_SLOPE * e;
      p = __expf(e);
    }
    s_src[wave][lane] = sv;
    s_p[wave][lane] = p;
    float ps = p;
    for (int o = 32; o; o >>= 1) ps += __shfl_xor(ps, o);
    sum += ps;
    int j = 0;
    for (; j + 8 <= m; j += 8) {
#pragma unroll
      for (int u = 0; u < 8; ++u) {
        int src = s_src[wave][j + u];
        float w = s_p[wave][j + u];
        uint2 pv = hp[(size_t)src * 64 + lane];
        a0 = fmaf(w, bf2f(pv.x & 0xffffu), a0);
        a1 = fmaf(w, bf2f(pv.x >> 16), a1);
        a2 = fmaf(w, bf2f(pv.y & 0xffffu), a2);
        a3 = fmaf(w, bf2f(pv.y >> 16), a3);
      }
    }
    for (; j < m; ++j) {
      int src = s_src[wave][j];
      float w = s_p[wave][j];
      uint2 pv = hp[(size_t)src * 64 + lane];
      a0 = fmaf(w, bf2f(pv.x & 0xffffu), a0);
      a1 = fmaf(w, bf2f(pv.x >> 16), a1);
      a2 = fmaf(w, bf2f(pv.y & 0xffffu), a2);
      a3 = fmaf(w, bf2f(pv.y >> 16), a3);
    }
  }
  float inv = 1.0f / sum;
  float4 b4 = ((const float4*)bias)[lane];
  float o0 = fmaxf(fmaf(a0, inv, b4.x), 0.f);
  float o1 = fmaxf(fmaf(a1, inv, b4.y), 0.f);
  float o2 = fmaxf(fmaf(a2, inv, b4.z), 0.f);
  float o3 = fmaxf(fmaf(a3, inv, b4.w), 0.f);
  uint2 ov;
  ov.x = (unsigned int)f2bf(o0) | ((unsigned int)f2bf(o1) << 16);
  ov.y = (unsigned int)f2bf(o2) | ((unsigned int)f2bf(o3) << 16);
  ((uint2*)outg)[(size_t)d * 64 + lane] = ov;
}

// ---- layer-3 softmax: single gather pass, stores p and 1/denom ----

__global__ void coeff3_kernel(const int* __restrict__ off, const int* __restrict__ esrc,
                              const float* __restrict__ as_, const float* __restrict__ ad_,
                              float* __restrict__ coeff, float* __restrict__ dinv) {
  int gid = blockIdx.x * blockDim.x + threadIdx.x;
  int d = gid >> 6, lane = threadIdx.x & 63;
  if (d >= N_NODES) return;
  int s0 = off[d], s1 = off[d + 1];
  float adv = ad_[d];
  float sum = 0.f;
  for (int s = s0 + lane; s < s1; s += 64) {
    float e = as_[esrc[s]] + adv;
    e = e > 0.f ? e : NEG_SLOPE * e;
    float p = __expf(e);
    coeff[s] = p;
    sum += p;
  }
  for (int o = 32; o; o >>= 1) sum += __shfl_xor(sum, o);
  if (lane == 0) dinv[d] = 1.0f / sum;
}

// ---- final aggregation, D=10 (4 dsts per wave), scaled by dinv ----

__global__ void agg10_kernel(const int* __restrict__ off, const int* __restrict__ esrc,
                             const float* __restrict__ coeff, const float* __restrict__ dinv,
                             const float* __restrict__ h, const float* __restrict__ bias,
                             float* __restrict__ out) {
  int gid = blockIdx.x * blockDim.x + threadIdx.x;
  int wid = gid >> 6;
  int lane = threadIdx.x & 63;
  int sub = lane >> 4, c = lane & 15;
  int d = wid * 4 + sub;
  if (d >= N_NODES || c >= 10) return;
  int s0 = off[d], s1 = off[d + 1];
  float acc = 0.f;
  for (int s = s0; s < s1; ++s)
    acc = fmaf(coeff[s], h[(size_t)esrc[s] * 10 + c], acc);
  out[(size_t)d * 10 + c] = fmaf(acc, dinv[d], bias[c]);
}

// ---------------- launch ----------------

extern "C" void kernel_launch(void* const* d_in, const int* in_sizes, int n_in,
                              void* d_out, int out_size, void* d_ws, size_t ws_size,
                              hipStream_t stream) {
  const float* x   = (const float*)d_in[0];
  const int*   ei  = (const int*)d_in[1];
  const float* W1  = (const float*)d_in[2];
  const float* as1 = (const float*)d_in[3];
  const float* ad1 = (const float*)d_in[4];
  const float* b1  = (const float*)d_in[5];
  const float* W2  = (const float*)d_in[6];
  const float* as2 = (const float*)d_in[7];
  const float* ad2 = (const float*)d_in[8];
  const float* b2  = (const float*)d_in[9];
  const float* W3  = (const float*)d_in[10];
  const float* as3 = (const float*)d_in[11];
  const float* ad3 = (const float*)d_in[12];
  const float* b3  = (const float*)d_in[13];
  float* out = (float*)d_out;

  char* ws = (char*)d_ws;
  size_t off_b = 0;
  auto alloc = [&](size_t bytes) -> char* {
    char* p = ws + off_b;
    off_b += (bytes + 255) & ~(size_t)255;
    return p;
  };
  unsigned short* hb   = (unsigned short*)alloc((size_t)N_NODES * 256 * 2);
  unsigned short* gb   = (unsigned short*)alloc((size_t)N_NODES * 256 * 2);
  unsigned short* Wf1  = (unsigned short*)alloc(256 * 256 * 2);
  unsigned short* Wf2  = (unsigned short*)alloc(256 * 256 * 2);
  unsigned short* Wf3  = (unsigned short*)alloc(8 * 64 * 8 * 2);
  float* h3    = (float*)alloc((size_t)N_NODES * 10 * 4);
  float* as_   = (float*)alloc((size_t)N_NODES * 4);
  float* ad_   = (float*)alloc((size_t)N_NODES * 4);
  float* dinv  = (float*)alloc((size_t)N_NODES * 4);
  int*   roff  = (int*)alloc((size_t)(N_NODES + 1) * 4);
  int*   cnt   = (int*)alloc((size_t)N_NODES * 4);
  int*   bsum  = (int*)alloc((size_t)SCAN_BLOCKS * 4);
  int*   bpre  = (int*)alloc((size_t)SCAN_BLOCKS * 4);
  int*   esrc  = (int*)alloc((size_t)EP * 4);
  float* coeff = (float*)alloc((size_t)EP * 4);

  cvt_wf_kernel<<<32, 256, 0, stream>>>(W1, Wf1);
  cvt_wf_kernel<<<32, 256, 0, stream>>>(W2, Wf2);
  cvt_wf3_kernel<<<2, 256, 0, stream>>>(W3, Wf3);

  // CSR build (once; graph identical across the 3 layers)
  hipMemsetAsync(cnt, 0, N_NODES * 4, stream);
  int eb = (EP + 255) / 256;
  count_kernel<<<eb, 256, 0, stream>>>(ei, cnt);
  scan1_kernel<<<SCAN_BLOCKS, 256, 0, stream>>>(cnt, roff, bsum);
  scan2_kernel<<<1, 256, 0, stream>>>(bsum, bpre, roff);
  scan3_kernel<<<SCAN_BLOCKS, 256, 0, stream>>>(roff, bpre);
  hipMemsetAsync(cnt, 0, N_NODES * 4, stream);
  scatter_kernel<<<eb, 256, 0, stream>>>(ei, roff, cnt, esrc);

  int gblocks = (N_NODES + 127) / 128;   // 391
  int ablocks = (N_NODES + 3) / 4;       // 12500
  int wgrid = (N_NODES * 64 + 255) / 256;
  int wgrid4 = (N_NODES * 16 + 255) / 256;

  // layer 1 (A = x in f32)
  gemm_mfma3<1><<<gblocks, 256, 0, stream>>>(x, (const uint4*)Wf1, hb, as1, ad1, as_, ad_, N_NODES);
  agg_fused_kernel<<<ablocks, 256, 0, stream>>>(roff, esrc, as_, ad_, hb, b1, gb);
  // layer 2
  gemm_mfma3<0><<<gblocks, 256, 0, stream>>>(gb, (const uint4*)Wf2, hb, as2, ad2, as_, ad_, N_NODES);
  agg_fused_kernel<<<ablocks, 256, 0, stream>>>(roff, esrc, as_, ad_, hb, b2, gb);
  // layer 3
  gemm_c3_kernel<<<gblocks, 256, 0, stream>>>(gb, Wf3, as3, ad3, h3, as_, ad_, N_NODES);
  coeff3_kernel<<<wgrid, 256, 0, stream>>>(roff, esrc, as_, ad_, coeff, dinv);
  agg10_kernel<<<wgrid4, 256, 0, stream>>>(roff, esrc, coeff, dinv, h3, b3, out);
}

// Round 5
// 379.349 us; speedup vs baseline: 2.6273x; 1.1290x over previous
//
#include <hip/hip_runtime.h>
#include <math.h>

#define N_NODES 50000
#define N_EDGES 800000
#define EP (N_EDGES + N_NODES) /* 850000 edges incl self-loops */
#define NEG_SLOPE 0.2f
#define SCAN_BLOCKS ((N_NODES + 255) / 256) /* 196 */

typedef short short8 __attribute__((ext_vector_type(8)));
typedef float float4_ __attribute__((ext_vector_type(4)));

__device__ __forceinline__ unsigned short f2bf(float f) {
  unsigned int u = __float_as_uint(f);
  u = (u + 0x7FFFu + ((u >> 16) & 1u)) >> 16;  // RNE
  return (unsigned short)u;
}
__device__ __forceinline__ float bf2f(unsigned int us) {
  return __uint_as_float(us << 16);
}
__device__ __forceinline__ unsigned int pack2(float lo, float hi) {
  return (unsigned int)f2bf(lo) | ((unsigned int)f2bf(hi) << 16);
}

// Column permutation: storage position p holds true column perm(p).
// GEMM epilogue: lane (kg,lm) packs acc[2j][i] (col 32j+lm) and acc[2j+1][i]
// (col 32j+16+lm) into uint j, written at short-offset r*256 + lm*16 + 2j.
// p = lm*16 + 2j + h  ->  c = 32j + 16h + lm.
__device__ __forceinline__ int permc(int p) {
  return ((p & 0xE) << 4) | ((p & 1) << 4) | (p >> 4);
}

// ---------------- conversions: W -> fragment-major bf16 (k optionally permuted) ----------------
// Wf[((nt*8 + k0t)*64 + lane)*8 + j] = bf16(W[ktrue(k0t*32 + kg*8 + j)*256 + nt*16 + lm])

template <int PERM>
__global__ void cvt_wf_kernel(const float* __restrict__ W, unsigned short* __restrict__ Wf) {
  int t = blockIdx.x * 256 + threadIdx.x;  // 8192 threads
  int f = t >> 6, lane = t & 63;
  int nt = f >> 3, k0t = f & 7;
  int lm = lane & 15, kg = lane >> 4;
  int kbase = k0t * 32 + kg * 8;
  int n = nt * 16 + lm;
  short8 v;
#pragma unroll
  for (int j = 0; j < 8; ++j) {
    int k = PERM ? permc(kbase + j) : (kbase + j);
    v[j] = (short)f2bf(W[(size_t)k * 256 + n]);
  }
  ((short8*)Wf)[t] = v;
}

// W3 [256][10] f32 -> 8 fragments (nt=0 only, cols padded to 16), k permuted
__global__ void cvt_wf3_kernel(const float* __restrict__ W3, unsigned short* __restrict__ Wf3) {
  int t = blockIdx.x * 256 + threadIdx.x;  // 512 threads
  int k0t = t >> 6, lane = t & 63;
  int lm = lane & 15, kg = lane >> 4;
  int kbase = k0t * 32 + kg * 8;
  short8 v;
#pragma unroll
  for (int j = 0; j < 8; ++j) {
    int k = permc(kbase + j);
    v[j] = (lm < 10) ? (short)f2bf(W3[(size_t)k * 10 + lm]) : (short)0;
  }
  ((short8*)Wf3)[t] = v;
}

__global__ void permute_bias_kernel(const float* __restrict__ b1, const float* __restrict__ b2,
                                    float* __restrict__ pb1, float* __restrict__ pb2) {
  int p = threadIdx.x;  // 256
  int c = permc(p);
  pb1[p] = b1[c];
  pb2[p] = b2[c];
}

// ---------------- CSR build ----------------

__global__ void count_kernel(const int* __restrict__ ei, int* __restrict__ cnt) {
  int e = blockIdx.x * 256 + threadIdx.x;
  if (e >= EP) return;
  int dst = (e < N_EDGES) ? ei[N_EDGES + e] : (e - N_EDGES);
  atomicAdd(&cnt[dst], 1);
}

__global__ void scan1_kernel(const int* __restrict__ cnt, int* __restrict__ off,
                             int* __restrict__ bsum) {
  int i = blockIdx.x * 256 + threadIdx.x;
  int v = (i < N_NODES) ? cnt[i] : 0;
  int lane = threadIdx.x & 63, w = threadIdx.x >> 6;
  int x = v;
  for (int o = 1; o < 64; o <<= 1) { int y = __shfl_up(x, o); if (lane >= o) x += y; }
  __shared__ int wsum[4];
  if (lane == 63) wsum[w] = x;
  __syncthreads();
  int add = 0;
  for (int k = 0; k < w; ++k) add += wsum[k];
  if (i < N_NODES) off[i] = x - v + add;  // block-local exclusive
  if (threadIdx.x == 255) bsum[blockIdx.x] = add + x;
}

__global__ void scan2_kernel(int* __restrict__ bsum, int* __restrict__ bpre,
                             int* __restrict__ off) {
  int t = threadIdx.x;
  int v = (t < SCAN_BLOCKS) ? bsum[t] : 0;
  int lane = t & 63, w = t >> 6;
  int x = v;
  for (int o = 1; o < 64; o <<= 1) { int y = __shfl_up(x, o); if (lane >= o) x += y; }
  __shared__ int wsum[4];
  if (lane == 63) wsum[w] = x;
  __syncthreads();
  int add = 0;
  for (int k = 0; k < w; ++k) add += wsum[k];
  if (t < SCAN_BLOCKS) bpre[t] = x - v + add;
  if (t == 255) off[N_NODES] = add + x;  // grand total == EP
}

__global__ void scan3_kernel(int* __restrict__ off, const int* __restrict__ bpre) {
  int i = blockIdx.x * 256 + threadIdx.x;
  if (i < N_NODES) off[i] += bpre[blockIdx.x];
}

__global__ void scatter_kernel(const int* __restrict__ ei, const int* __restrict__ off,
                               int* __restrict__ cnt, int* __restrict__ esrc) {
  int e = blockIdx.x * 256 + threadIdx.x;
  if (e >= EP) return;
  int src, dst;
  if (e < N_EDGES) { src = ei[e]; dst = ei[N_EDGES + e]; }
  else { src = dst = e - N_EDGES; }
  int pos = off[dst] + atomicAdd(&cnt[dst], 1);
  esrc[pos] = src;
}

// ---- bf16 MFMA GEMM, B in LDS, permuted-C epilogue + fused alpha ----
// 512 threads = 8 waves, 32 rows/wave -> 256 rows/block; grid = 196 blocks.

template <int AF32>
__global__ __launch_bounds__(512, 2) void gemm_mfma4(const void* __restrict__ Av,
                                                     const uint4* __restrict__ Wf,
                                                     unsigned short* __restrict__ C,
                                                     const float* __restrict__ asrc,
                                                     const float* __restrict__ adst,
                                                     float* __restrict__ as_,
                                                     float* __restrict__ ad_, int M) {
  __shared__ uint4 Bl[8192];  // 128 KB
  int tid = threadIdx.x;
#pragma unroll
  for (int i = 0; i < 16; ++i) Bl[i * 512 + tid] = Wf[i * 512 + tid];
  int wave = tid >> 6, lane = tid & 63;
  int lm = lane & 15, kg = lane >> 4;
  int row0 = blockIdx.x * 256 + wave * 32;
  int ar0 = row0 + lm, ar1 = row0 + 16 + lm;
  if (ar0 >= M) ar0 = M - 1;
  if (ar1 >= M) ar1 = M - 1;
  float4_ acc0[16], acc1[16];
#pragma unroll
  for (int i = 0; i < 16; ++i) { acc0[i] = (float4_){0, 0, 0, 0}; acc1[i] = (float4_){0, 0, 0, 0}; }
  __syncthreads();
  const short8* Bf = (const short8*)Bl;
  for (int k0t = 0; k0t < 8; ++k0t) {
    int k0 = k0t * 32;
    short8 a0, a1;
    if (AF32) {
      const float* A = (const float*)Av;
      const float* p0 = A + (size_t)ar0 * 256 + kg * 8 + k0;
      const float* p1 = A + (size_t)ar1 * 256 + kg * 8 + k0;
      float4 f0 = *(const float4*)p0, f1 = *(const float4*)(p0 + 4);
      float4 g0 = *(const float4*)p1, g1 = *(const float4*)(p1 + 4);
      a0 = (short8){(short)f2bf(f0.x), (short)f2bf(f0.y), (short)f2bf(f0.z), (short)f2bf(f0.w),
                    (short)f2bf(f1.x), (short)f2bf(f1.y), (short)f2bf(f1.z), (short)f2bf(f1.w)};
      a1 = (short8){(short)f2bf(g0.x), (short)f2bf(g0.y), (short)f2bf(g0.z), (short)f2bf(g0.w),
                    (short)f2bf(g1.x), (short)f2bf(g1.y), (short)f2bf(g1.z), (short)f2bf(g1.w)};
    } else {
      const unsigned short* A = (const unsigned short*)Av;
      a0 = *(const short8*)(A + (size_t)ar0 * 256 + kg * 8 + k0);
      a1 = *(const short8*)(A + (size_t)ar1 * 256 + kg * 8 + k0);
    }
#pragma unroll
    for (int nt = 0; nt < 16; ++nt) {
      short8 b = Bf[(nt * 8 + k0t) * 64 + lane];
      acc0[nt] = __builtin_amdgcn_mfma_f32_16x16x32_bf16(a0, b, acc0[nt], 0, 0, 0);
      acc1[nt] = __builtin_amdgcn_mfma_f32_16x16x32_bf16(a1, b, acc1[nt], 0, 0, 0);
    }
  }
  // epilogue: permuted-C coalesced stores + fused alpha (from fp32 acc, true cols)
  float avs[16], avd[16];
#pragma unroll
  for (int nt = 0; nt < 16; ++nt) { avs[nt] = asrc[nt * 16 + lm]; avd[nt] = adst[nt * 16 + lm]; }
#pragma unroll
  for (int g = 0; g < 2; ++g) {
    int rbase = row0 + g * 16 + kg * 4;
#pragma unroll
    for (int i = 0; i < 4; ++i) {
      int r = rbase + i;
      float s = 0.f, dd = 0.f;
      unsigned int u[8];
#pragma unroll
      for (int j = 0; j < 8; ++j) {
        float vlo = g ? acc1[2 * j][i] : acc0[2 * j][i];
        float vhi = g ? acc1[2 * j + 1][i] : acc0[2 * j + 1][i];
        u[j] = pack2(vlo, vhi);
        s += vlo * avs[2 * j] + vhi * avs[2 * j + 1];
        dd += vlo * avd[2 * j] + vhi * avd[2 * j + 1];
      }
      if (r < M) {
        uint4* cp = (uint4*)(C + (size_t)r * 256 + lm * 16);
        cp[0] = (uint4){u[0], u[1], u[2], u[3]};
        cp[1] = (uint4){u[4], u[5], u[6], u[7]};
      }
#pragma unroll
      for (int o = 1; o < 16; o <<= 1) { s += __shfl_xor(s, o); dd += __shfl_xor(dd, o); }
      if (lm == 0 && r < M) { as_[r] = s; ad_[r] = dd; }
    }
  }
}

// ---- layer-3 MFMA GEMM: permuted-k A @ permuted-k Wf3 + fused alpha ----

__global__ __launch_bounds__(256) void gemm_c3_kernel(const unsigned short* __restrict__ X,
                                                      const unsigned short* __restrict__ Wf3,
                                                      const float* __restrict__ asrc,
                                                      const float* __restrict__ adst,
                                                      float* __restrict__ h3,
                                                      float* __restrict__ as_,
                                                      float* __restrict__ ad_, int M) {
  int tid = threadIdx.x;
  int wave = tid >> 6, lane = tid & 63;
  int lm = lane & 15, kg = lane >> 4;
  int row0 = blockIdx.x * 128 + wave * 32;
  int ar0 = row0 + lm, ar1 = row0 + 16 + lm;
  if (ar0 >= M) ar0 = M - 1;
  if (ar1 >= M) ar1 = M - 1;
  short8 bf[8];
#pragma unroll
  for (int k0t = 0; k0t < 8; ++k0t) bf[k0t] = ((const short8*)Wf3)[k0t * 64 + lane];
  float4_ acc0 = (float4_){0, 0, 0, 0}, acc1 = (float4_){0, 0, 0, 0};
#pragma unroll
  for (int k0t = 0; k0t < 8; ++k0t) {
    int k0 = k0t * 32;
    short8 a0 = *(const short8*)(X + (size_t)ar0 * 256 + kg * 8 + k0);
    short8 a1 = *(const short8*)(X + (size_t)ar1 * 256 + kg * 8 + k0);
    acc0 = __builtin_amdgcn_mfma_f32_16x16x32_bf16(a0, bf[k0t], acc0, 0, 0, 0);
    acc1 = __builtin_amdgcn_mfma_f32_16x16x32_bf16(a1, bf[k0t], acc1, 0, 0, 0);
  }
  float avs = (lm < 10) ? asrc[lm] : 0.f;
  float avd = (lm < 10) ? adst[lm] : 0.f;
#pragma unroll
  for (int g = 0; g < 2; ++g) {
    int rbase = row0 + g * 16 + kg * 4;
#pragma unroll
    for (int i = 0; i < 4; ++i) {
      int r = rbase + i;
      float v = g ? acc1[i] : acc0[i];
      if (r < M && lm < 10) h3[(size_t)r * 10 + lm] = v;
      float s = v * avs, dd = v * avd;
#pragma unroll
      for (int o = 1; o < 16; o <<= 1) { s += __shfl_xor(s, o); dd += __shfl_xor(dd, o); }
      if (lm == 0 && r < M) { as_[r] = s; ad_[r] = dd; }
    }
  }
}

// ---- fused softmax + aggregation (layers 1&2): one wave per dst, 2 edges/load ----
// Half-waves (32 lanes x uint4 = 1 KB/instr) each take one edge; shfl_xor(32) combines.

__global__ __launch_bounds__(256) void agg_fused_kernel(const int* __restrict__ off,
                                                        const int* __restrict__ esrc,
                                                        const float* __restrict__ as_,
                                                        const float* __restrict__ ad_,
                                                        const unsigned short* __restrict__ h,
                                                        const float* __restrict__ pbias,
                                                        unsigned short* __restrict__ outg) {
  __shared__ int s_src[4][64];
  __shared__ float s_p[4][64];
  int wave = threadIdx.x >> 6, lane = threadIdx.x & 63;
  int pair = lane >> 5, cl = lane & 31;  // lane covers storage cols [8*cl, 8*cl+8)
  int d = blockIdx.x * 4 + wave;
  int s0 = off[d], s1 = off[d + 1];
  float adv = ad_[d];
  const uint4* hp4 = (const uint4*)h;
  float a0 = 0.f, a1 = 0.f, a2 = 0.f, a3 = 0.f, a4 = 0.f, a5 = 0.f, a6 = 0.f, a7 = 0.f;
  float sum = 0.f;
  for (int base = s0; base < s1; base += 64) {
    int m = s1 - base; if (m > 64) m = 64;
    int sv = 0; float p = 0.f;
    if (lane < m) {
      sv = esrc[base + lane];
      float e = as_[sv] + adv;
      e = e > 0.f ? e : NEG_SLOPE * e;
      p = __expf(e);
    }
    s_src[wave][lane] = sv;
    s_p[wave][lane] = p;
    float ps = p;
    for (int o = 32; o; o >>= 1) ps += __shfl_xor(ps, o);
    sum += ps;
    int nb = (m + 1) >> 1;  // batches of 2 edges (one per half-wave)
    int j = 0;
    for (; j + 4 <= nb; j += 4) {
#pragma unroll
      for (int u = 0; u < 4; ++u) {
        int idx = (j + u) * 2 + pair;
        int src = s_src[wave][idx];
        float w = s_p[wave][idx];
        uint4 pv = hp4[(size_t)src * 32 + cl];
        a0 = fmaf(w, bf2f(pv.x & 0xffffu), a0); a1 = fmaf(w, bf2f(pv.x >> 16), a1);
        a2 = fmaf(w, bf2f(pv.y & 0xffffu), a2); a3 = fmaf(w, bf2f(pv.y >> 16), a3);
        a4 = fmaf(w, bf2f(pv.z & 0xffffu), a4); a5 = fmaf(w, bf2f(pv.z >> 16), a5);
        a6 = fmaf(w, bf2f(pv.w & 0xffffu), a6); a7 = fmaf(w, bf2f(pv.w >> 16), a7);
      }
    }
    for (; j < nb; ++j) {
      int idx = j * 2 + pair;
      int src = s_src[wave][idx];
      float w = s_p[wave][idx];
      uint4 pv = hp4[(size_t)src * 32 + cl];
      a0 = fmaf(w, bf2f(pv.x & 0xffffu), a0); a1 = fmaf(w, bf2f(pv.x >> 16), a1);
      a2 = fmaf(w, bf2f(pv.y & 0xffffu), a2); a3 = fmaf(w, bf2f(pv.y >> 16), a3);
      a4 = fmaf(w, bf2f(pv.z & 0xffffu), a4); a5 = fmaf(w, bf2f(pv.z >> 16), a5);
      a6 = fmaf(w, bf2f(pv.w & 0xffffu), a6); a7 = fmaf(w, bf2f(pv.w >> 16), a7);
    }
  }
  a0 += __shfl_xor(a0, 32); a1 += __shfl_xor(a1, 32);
  a2 += __shfl_xor(a2, 32); a3 += __shfl_xor(a3, 32);
  a4 += __shfl_xor(a4, 32); a5 += __shfl_xor(a5, 32);
  a6 += __shfl_xor(a6, 32); a7 += __shfl_xor(a7, 32);
  if (pair == 0) {
    float inv = 1.0f / sum;
    float4 b0 = ((const float4*)pbias)[2 * cl];
    float4 b1 = ((const float4*)pbias)[2 * cl + 1];
    float o0 = fmaxf(fmaf(a0, inv, b0.x), 0.f);
    float o1 = fmaxf(fmaf(a1, inv, b0.y), 0.f);
    float o2 = fmaxf(fmaf(a2, inv, b0.z), 0.f);
    float o3 = fmaxf(fmaf(a3, inv, b0.w), 0.f);
    float o4 = fmaxf(fmaf(a4, inv, b1.x), 0.f);
    float o5 = fmaxf(fmaf(a5, inv, b1.y), 0.f);
    float o6 = fmaxf(fmaf(a6, inv, b1.z), 0.f);
    float o7 = fmaxf(fmaf(a7, inv, b1.w), 0.f);
    uint4 ov = (uint4){pack2(o0, o1), pack2(o2, o3), pack2(o4, o5), pack2(o6, o7)};
    ((uint4*)outg)[(size_t)d * 32 + cl] = ov;
  }
}

// ---- layer-3 fused softmax+agg, D=10: 16-lane group per dst, p on the fly ----

__global__ void agg10_fused_kernel(const int* __restrict__ off, const int* __restrict__ esrc,
                                   const float* __restrict__ as_, const float* __restrict__ ad_,
                                   const float* __restrict__ h, const float* __restrict__ bias,
                                   float* __restrict__ out) {
  int gid = blockIdx.x * 256 + threadIdx.x;
  int wid = gid >> 6, lane = threadIdx.x & 63;
  int g = lane >> 4, c = lane & 15;
  int d = wid * 4 + g;
  if (d >= N_NODES) return;
  int s0 = off[d], s1 = off[d + 1];
  float adv = ad_[d];
  float acc = 0.f, sum = 0.f;
  int s = s0;
  for (; s + 2 <= s1; s += 2) {
    int i0 = esrc[s], i1 = esrc[s + 1];
    float e0 = as_[i0] + adv; e0 = e0 > 0.f ? e0 : NEG_SLOPE * e0;
    float e1 = as_[i1] + adv; e1 = e1 > 0.f ? e1 : NEG_SLOPE * e1;
    float h0 = (c < 10) ? h[(size_t)i0 * 10 + c] : 0.f;
    float h1 = (c < 10) ? h[(size_t)i1 * 10 + c] : 0.f;
    float p0 = __expf(e0), p1 = __expf(e1);
    acc = fmaf(p0, h0, acc);
    acc = fmaf(p1, h1, acc);
    sum += p0 + p1;
  }
  if (s < s1) {
    int i0 = esrc[s];
    float e0 = as_[i0] + adv; e0 = e0 > 0.f ? e0 : NEG_SLOPE * e0;
    float p0 = __expf(e0);
    if (c < 10) acc = fmaf(p0, h[(size_t)i0 * 10 + c], acc);
    sum += p0;
  }
  if (c < 10) out[(size_t)d * 10 + c] = fmaf(acc, 1.0f / sum, bias[c]);
}

// ---------------- launch ----------------

extern "C" void kernel_launch(void* const* d_in, const int* in_sizes, int n_in,
                              void* d_out, int out_size, void* d_ws, size_t ws_size,
                              hipStream_t stream) {
  const float* x   = (const float*)d_in[0];
  const int*   ei  = (const int*)d_in[1];
  const float* W1  = (const float*)d_in[2];
  const float* as1 = (const float*)d_in[3];
  const float* ad1 = (const float*)d_in[4];
  const float* b1  = (const float*)d_in[5];
  const float* W2  = (const float*)d_in[6];
  const float* as2 = (const float*)d_in[7];
  const float* ad2 = (const float*)d_in[8];
  const float* b2  = (const float*)d_in[9];
  const float* W3  = (const float*)d_in[10];
  const float* as3 = (const float*)d_in[11];
  const float* ad3 = (const float*)d_in[12];
  const float* b3  = (const float*)d_in[13];
  float* out = (float*)d_out;

  char* ws = (char*)d_ws;
  size_t off_b = 0;
  auto alloc = [&](size_t bytes) -> char* {
    char* p = ws + off_b;
    off_b += (bytes + 255) & ~(size_t)255;
    return p;
  };
  unsigned short* hb   = (unsigned short*)alloc((size_t)N_NODES * 256 * 2);
  unsigned short* gb   = (unsigned short*)alloc((size_t)N_NODES * 256 * 2);
  unsigned short* Wf1  = (unsigned short*)alloc(256 * 256 * 2);
  unsigned short* Wf2  = (unsigned short*)alloc(256 * 256 * 2);
  unsigned short* Wf3  = (unsigned short*)alloc(8 * 64 * 8 * 2);
  float* pb1   = (float*)alloc(256 * 4);
  float* pb2   = (float*)alloc(256 * 4);
  float* h3    = (float*)alloc((size_t)N_NODES * 10 * 4);
  float* as_   = (float*)alloc((size_t)N_NODES * 4);
  float* ad_   = (float*)alloc((size_t)N_NODES * 4);
  int*   roff  = (int*)alloc((size_t)(N_NODES + 1) * 4);
  int*   cnt   = (int*)alloc((size_t)N_NODES * 4);
  int*   bsum  = (int*)alloc((size_t)SCAN_BLOCKS * 4);
  int*   bpre  = (int*)alloc((size_t)SCAN_BLOCKS * 4);
  int*   esrc  = (int*)alloc((size_t)EP * 4);

  cvt_wf_kernel<0><<<32, 256, 0, stream>>>(W1, Wf1);
  cvt_wf_kernel<1><<<32, 256, 0, stream>>>(W2, Wf2);
  cvt_wf3_kernel<<<2, 256, 0, stream>>>(W3, Wf3);
  permute_bias_kernel<<<1, 256, 0, stream>>>(b1, b2, pb1, pb2);

  // CSR build (once; graph identical across the 3 layers)
  hipMemsetAsync(cnt, 0, N_NODES * 4, stream);
  int eb = (EP + 255) / 256;
  count_kernel<<<eb, 256, 0, stream>>>(ei, cnt);
  scan1_kernel<<<SCAN_BLOCKS, 256, 0, stream>>>(cnt, roff, bsum);
  scan2_kernel<<<1, 256, 0, stream>>>(bsum, bpre, roff);
  scan3_kernel<<<SCAN_BLOCKS, 256, 0, stream>>>(roff, bpre);
  hipMemsetAsync(cnt, 0, N_NODES * 4, stream);
  scatter_kernel<<<eb, 256, 0, stream>>>(ei, roff, cnt, esrc);

  int g4blocks = (N_NODES + 255) / 256;  // 196
  int g3blocks = (N_NODES + 127) / 128;  // 391
  int ablocks = (N_NODES + 3) / 4;       // 12500
  int wgrid4 = (N_NODES * 16 + 255) / 256;

  // layer 1 (A = x in f32; C permuted)
  gemm_mfma4<1><<<g4blocks, 512, 0, stream>>>(x, (const uint4*)Wf1, hb, as1, ad1, as_, ad_, N_NODES);
  agg_fused_kernel<<<ablocks, 256, 0, stream>>>(roff, esrc, as_, ad_, hb, pb1, gb);
  // layer 2 (A = gb permuted; Wf2 k-permuted to match)
  gemm_mfma4<0><<<g4blocks, 512, 0, stream>>>(gb, (const uint4*)Wf2, hb, as2, ad2, as_, ad_, N_NODES);
  agg_fused_kernel<<<ablocks, 256, 0, stream>>>(roff, esrc, as_, ad_, hb, pb2, gb);
  // layer 3 (Wf3 k-permuted; output true cols)
  gemm_c3_kernel<<<g3blocks, 256, 0, stream>>>(gb, Wf3, as3, ad3, h3, as_, ad_, N_NODES);
  agg10_fused_kernel<<<wgrid4, 256, 0, stream>>>(roff, esrc, as_, ad_, h3, b3, out);
}